// Round 7
// baseline (552.107 us; speedup 1.0000x reference)
//
#include <hip/hip_runtime.h>

typedef __attribute__((ext_vector_type(8))) __bf16 bf16x8;
typedef __attribute__((ext_vector_type(4))) float f32x4;

#define SLEN 1024
#define DMODEL 1024
#define NHEADS 16
#define DKH 64
#define BATCH 8

__device__ __forceinline__ unsigned short f2bf(float f) {
  unsigned u = __builtin_bit_cast(unsigned, f);
  u += 0x7FFFu + ((u >> 16) & 1u);
  return (unsigned short)(u >> 16);
}

__device__ __forceinline__ void gload_lds16(const void* g, void* l) {
  __builtin_amdgcn_global_load_lds((const __attribute__((address_space(1))) unsigned int*)g,
                                   (__attribute__((address_space(3))) unsigned int*)l, 16, 0, 0);
}

// ---------------- mask dtype detection: flag=1 -> byte mask, 0 -> int32 mask
__global__ void detect_mask(const unsigned char* __restrict__ m, int* __restrict__ flag) {
  int t = threadIdx.x;
  unsigned any = 0;
  for (int j = t; j < 4096; j += 64) any |= m[j * 4 + 1];
  unsigned long long b = __ballot(any != 0);
  if (t == 0) *flag = (b != 0) ? 1 : 0;
}

// ---------------- bit-pack mask: one block per (b,q) row of 1024 -> 32 words
__global__ __launch_bounds__(256) void mask_pack(const unsigned char* __restrict__ m,
                                                 const int* __restrict__ flagp,
                                                 unsigned* __restrict__ mb) {
  long base = (long)blockIdx.x << 10;
  int tid = threadIdx.x;
  int flag = *flagp;
  unsigned nib;
  if (flag) {
    uchar4 v = ((const uchar4*)(m + base))[tid];
    nib = (v.x ? 1u : 0u) | (v.y ? 2u : 0u) | (v.z ? 4u : 0u) | (v.w ? 8u : 0u);
  } else {
    int4 v = ((const int4*)((const int*)m + base))[tid];
    nib = (v.x ? 1u : 0u) | (v.y ? 2u : 0u) | (v.z ? 4u : 0u) | (v.w ? 8u : 0u);
  }
  __shared__ unsigned char nibs[256];
  nibs[tid] = (unsigned char)nib;
  __syncthreads();
  if (tid < 32) {
    unsigned wv = 0;
#pragma unroll
    for (int i = 0; i < 8; i++) wv |= ((unsigned)nibs[tid * 8 + i]) << (i * 4);
    mb[((long)blockIdx.x << 5) + tid] = wv;
  }
}

// ---------------- fp32 -> bf16 bulk convert, 4 weight tensors via blockIdx.y
__global__ __launch_bounds__(256) void cvt_bf16_multi(
    const float* __restrict__ p0, const float* __restrict__ p1,
    const float* __restrict__ p2, const float* __restrict__ p3,
    unsigned short* __restrict__ o0, unsigned short* __restrict__ o1,
    unsigned short* __restrict__ o2, unsigned short* __restrict__ o3, int n8) {
  int which = blockIdx.y;
  const float* in = which == 0 ? p0 : which == 1 ? p1 : which == 2 ? p2 : p3;
  unsigned short* o = which == 0 ? o0 : which == 1 ? o1 : which == 2 ? o2 : o3;
  int i = blockIdx.x * 256 + threadIdx.x;
  if (i >= n8) return;
  const float4* p = (const float4*)in;
  float4 f0 = p[2 * i], f1 = p[2 * i + 1];
  union { unsigned short us[8]; uint4 v; } pk;
  pk.us[0] = f2bf(f0.x); pk.us[1] = f2bf(f0.y); pk.us[2] = f2bf(f0.z); pk.us[3] = f2bf(f0.w);
  pk.us[4] = f2bf(f1.x); pk.us[5] = f2bf(f1.y); pk.us[6] = f2bf(f1.z); pk.us[7] = f2bf(f1.w);
  ((uint4*)o)[i] = pk.v;
}

// ---------------- transpose V per (b,h): [1024][64] -> [64][1024]
__global__ __launch_bounds__(256) void transpose_v(const unsigned short* __restrict__ Vh,
                                                   unsigned short* __restrict__ Vt) {
  __shared__ unsigned short t[64][65];
  int s0 = blockIdx.x * 64;
  long zo = (long)blockIdx.y * (SLEN * DKH);
  int tid = threadIdx.x;
  for (int i = tid; i < 4096; i += 256) {
    int r = i >> 6, c = i & 63;
    t[r][c] = Vh[zo + (long)(s0 + r) * 64 + c];
  }
  __syncthreads();
  for (int i = tid; i < 4096; i += 256) {
    int d = i >> 6, sc = i & 63;
    Vt[zo + (long)d * SLEN + s0 + sc] = t[sc][d];
  }
}

// ---------------- merged QKV projection GEMM (z = 0/1/2 -> Q/K/V)
// A = fp32 input (converted during reg-staging), B = bf16 weights.
// BK=64, XOR-swizzled LDS (both sides). grid (8 n-tiles, 64 m-tiles, 3).
__global__ __launch_bounds__(256) void gemm_proj3(
    const float* __restrict__ A0, const float* __restrict__ A1,
    const float* __restrict__ A2, const unsigned short* __restrict__ B0,
    const unsigned short* __restrict__ B1, const unsigned short* __restrict__ B2,
    unsigned short* __restrict__ O0, unsigned short* __restrict__ O1,
    unsigned short* __restrict__ O2) {
  const int z = blockIdx.z;
  const float* Af = z == 0 ? A0 : z == 1 ? A1 : A2;
  const unsigned short* Bb = z == 0 ? B0 : z == 1 ? B1 : B2;
  unsigned short* obf = z == 0 ? O0 : z == 1 ? O1 : O2;
  const float scale = z == 0 ? 0.125f : 1.0f;

  const int n0 = blockIdx.x * 128;
  const int m0 = blockIdx.y * 128;
  const int tid = threadIdx.x;
  const int l = tid & 63;
  const int w = tid >> 6;
  const int wr = w >> 1, wc = w & 1;
  const int rl = l & 15, hi = l >> 4;

  __shared__ __attribute__((aligned(16))) unsigned short As[128 * 64];  // 16 KB swz
  __shared__ __attribute__((aligned(16))) unsigned short Bs[128 * 64];  // 16 KB swz

  f32x4 acc[4][4];
#pragma unroll
  for (int i = 0; i < 4; i++)
#pragma unroll
    for (int j = 0; j < 4; j++) acc[i][j] = f32x4{0.f, 0.f, 0.f, 0.f};

  for (int k0 = 0; k0 < 1024; k0 += 64) {
    __syncthreads();
    // A: 128x64 fp32 -> bf16, swizzled ds_write (16 elems/thread/iter, 2 iters)
#pragma unroll
    for (int i = 0; i < 2; i++) {
      int c = i * 256 + tid;
      int row = c >> 2, kc = (c & 3) << 4;  // 16-elem chunk
      const float* src = Af + (long)(m0 + row) * 1024 + k0 + kc;
      float4 f0 = ((const float4*)src)[0];
      float4 f1 = ((const float4*)src)[1];
      float4 f2 = ((const float4*)src)[2];
      float4 f3 = ((const float4*)src)[3];
      union { unsigned short us[8]; uint4 v; } pa, pb;
      pa.us[0] = f2bf(f0.x); pa.us[1] = f2bf(f0.y); pa.us[2] = f2bf(f0.z); pa.us[3] = f2bf(f0.w);
      pa.us[4] = f2bf(f1.x); pa.us[5] = f2bf(f1.y); pa.us[6] = f2bf(f1.z); pa.us[7] = f2bf(f1.w);
      pb.us[0] = f2bf(f2.x); pb.us[1] = f2bf(f2.y); pb.us[2] = f2bf(f2.z); pb.us[3] = f2bf(f2.w);
      pb.us[4] = f2bf(f3.x); pb.us[5] = f2bf(f3.y); pb.us[6] = f2bf(f3.z); pb.us[7] = f2bf(f3.w);
      int c0 = kc >> 3, sw = row & 7;
      *(uint4*)((char*)As + row * 128 + ((c0 ^ sw) << 4)) = pa.v;
      *(uint4*)((char*)As + row * 128 + (((c0 + 1) ^ sw) << 4)) = pb.v;
    }
    // B: 128x64 bf16 via gload_lds, pre-swizzled source (4 iters)
#pragma unroll
    for (int i = 0; i < 4; i++) {
      int o = (i * 256 + tid) * 16;
      int row = o >> 7, cb = o & 127;
      int cbs = cb ^ ((row & 7) << 4);
      gload_lds16(Bb + (long)(n0 + row) * 1024 + k0 + (cbs >> 1), (char*)Bs + o);
    }
    __syncthreads();

#pragma unroll
    for (int ks = 0; ks < 2; ks++) {
      int kb = ks * 64 + hi * 16;
      bf16x8 af[4], bfr[4];
#pragma unroll
      for (int mi = 0; mi < 4; mi++) {
        int row = wr * 64 + mi * 16 + rl;
        af[mi] = *(const bf16x8*)((const char*)As + row * 128 + (kb ^ ((row & 7) << 4)));
      }
#pragma unroll
      for (int ni = 0; ni < 4; ni++) {
        int row = wc * 64 + ni * 16 + rl;
        bfr[ni] = *(const bf16x8*)((const char*)Bs + row * 128 + (kb ^ ((row & 7) << 4)));
      }
#pragma unroll
      for (int mi = 0; mi < 4; mi++)
#pragma unroll
        for (int ni = 0; ni < 4; ni++)
          acc[mi][ni] = __builtin_amdgcn_mfma_f32_16x16x32_bf16(af[mi], bfr[ni], acc[mi][ni], 0, 0, 0);
    }
  }

  const int r0 = hi << 2;
#pragma unroll
  for (int mi = 0; mi < 4; mi++) {
#pragma unroll
    for (int ni = 0; ni < 4; ni++) {
      f32x4 v = acc[mi][ni];
      int row = m0 + wr * 64 + mi * 16 + r0;
      int col = n0 + wc * 64 + ni * 16 + rl;
#pragma unroll
      for (int j = 0; j < 4; j++) {
        int rr = row + j;
        long idx = (((long)((rr >> 10) * 16 + (col >> 6)) * 1024 + (rr & 1023)) << 6) + (col & 63);
        obf[idx] = f2bf(v[j] * scale);
      }
    }
  }
}

// ---------------- fused FC + residual + LayerNorm
// BM=16, BN=1024 (full row in block): 512 thr, 8 waves, wave w owns cols [w*128,+128)
// Wfc read direct from L2 (2 MB, per-XCD resident); A staged swizzled in LDS.
__global__ __launch_bounds__(512) void gemm_fc_ln(
    const unsigned short* __restrict__ ctx, const unsigned short* __restrict__ Wfc,
    const float* __restrict__ inQ, const float* __restrict__ gamma,
    const float* __restrict__ beta, float* __restrict__ out) {
  const int m0 = blockIdx.x * 16;
  const int tid = threadIdx.x;
  const int l = tid & 63, w = tid >> 6;
  const int rl = l & 15, hi = l >> 4;

  __shared__ __attribute__((aligned(16))) unsigned short As[16 * 64];  // 2 KB swz
  __shared__ float rsum[8][16], rsq[8][16];

  f32x4 acc[8];
#pragma unroll
  for (int i = 0; i < 8; i++) acc[i] = f32x4{0.f, 0.f, 0.f, 0.f};

  for (int k0 = 0; k0 < 1024; k0 += 64) {
    __syncthreads();
    if (tid < 128) {
      int o = tid * 16;
      int row = o >> 7, cb = o & 127;
      int cbs = cb ^ ((row & 7) << 4);
      gload_lds16(ctx + (long)(m0 + row) * 1024 + k0 + (cbs >> 1), (char*)As + o);
    }
    __syncthreads();

#pragma unroll
    for (int ks = 0; ks < 2; ks++) {
      int kb = ks * 64 + hi * 16;
      bf16x8 af = *(const bf16x8*)((const char*)As + rl * 128 + (kb ^ ((rl & 7) << 4)));
#pragma unroll
      for (int nf = 0; nf < 8; nf++) {
        int bn = w * 128 + nf * 16 + rl;
        bf16x8 bf = *(const bf16x8*)(Wfc + (long)bn * 1024 + k0 + ks * 32 + hi * 8);
        acc[nf] = __builtin_amdgcn_mfma_f32_16x16x32_bf16(af, bf, acc[nf], 0, 0, 0);
      }
    }
  }

  // residual + row stats
  float s[4] = {0.f, 0.f, 0.f, 0.f}, q2[4] = {0.f, 0.f, 0.f, 0.f};
#pragma unroll
  for (int nf = 0; nf < 8; nf++) {
    int col = w * 128 + nf * 16 + rl;
#pragma unroll
    for (int j = 0; j < 4; j++) {
      int r = hi * 4 + j;
      float x = acc[nf][j] + inQ[(long)(m0 + r) * 1024 + col];
      acc[nf][j] = x;
      s[j] += x;
      q2[j] += x * x;
    }
  }
#pragma unroll
  for (int j = 0; j < 4; j++) {
    s[j] += __shfl_xor(s[j], 1);  q2[j] += __shfl_xor(q2[j], 1);
    s[j] += __shfl_xor(s[j], 2);  q2[j] += __shfl_xor(q2[j], 2);
    s[j] += __shfl_xor(s[j], 4);  q2[j] += __shfl_xor(q2[j], 4);
    s[j] += __shfl_xor(s[j], 8);  q2[j] += __shfl_xor(q2[j], 8);
  }
  if (rl == 0) {
#pragma unroll
    for (int j = 0; j < 4; j++) {
      rsum[w][hi * 4 + j] = s[j];
      rsq[w][hi * 4 + j] = q2[j];
    }
  }
  __syncthreads();
  float mu[4], rstd[4];
#pragma unroll
  for (int j = 0; j < 4; j++) {
    int r = hi * 4 + j;
    float ss = 0.f, qq = 0.f;
#pragma unroll
    for (int ww = 0; ww < 8; ww++) { ss += rsum[ww][r]; qq += rsq[ww][r]; }
    mu[j] = ss * (1.0f / 1024.0f);
    float var = qq * (1.0f / 1024.0f) - mu[j] * mu[j];
    rstd[j] = rsqrtf(var + 1e-5f);
  }
#pragma unroll
  for (int nf = 0; nf < 8; nf++) {
    int col = w * 128 + nf * 16 + rl;
    float g = gamma[col], be = beta[col];
#pragma unroll
    for (int j = 0; j < 4; j++) {
      int r = hi * 4 + j;
      out[(long)(m0 + r) * 1024 + col] = (acc[nf][j] - mu[j]) * rstd[j] * g + be;
    }
  }
}

// ---------------- fused scores+mask+softmax+attnwrite+PV, K/V L2-direct
// 1-D grid 1024; XCD-locality decode: each XCD owns 16 z's (K+V = 4 MB = its L2)
__global__ __launch_bounds__(256) void attn_fused2(
    const unsigned short* __restrict__ Qh, const unsigned short* __restrict__ Kh,
    const unsigned short* __restrict__ Vt, const unsigned* __restrict__ mb,
    float* __restrict__ attn, unsigned short* __restrict__ ctx) {
  const int lin = blockIdx.x;
  const int xcd = lin & 7;
  const int k_ = lin >> 3;
  const int z = xcd + ((k_ >> 3) << 3);  // z % 8 == xcd
  const int qt = k_ & 7;
  const int b = z >> 4, h = z & 15;
  const int tid = threadIdx.x, l = tid & 63, w = tid >> 6;
  const int rl = l & 15, hi = l >> 4;

  __shared__ __attribute__((aligned(16))) unsigned short Pl[16 * 1024];  // 32 KB swz
  __shared__ __attribute__((aligned(16))) unsigned short Pc[16 * 64];    // 2 KB
  __shared__ float redm[4][16], reds[4][16];

  const long bh = (long)z * (SLEN * DKH);
  const unsigned short* Kb = Kh + bh;
  const unsigned short* Vb = Vt + bh;
  const long abase = (long)z << 20;

  for (int s = 0; s < 8; s++) {
    const int q0 = qt * 128 + s * 16;
    const unsigned short* qp = Qh + bh + (long)(q0 + rl) * 64 + hi * 8;
    bf16x8 qf0 = *(const bf16x8*)qp;
    bf16x8 qf1 = *(const bf16x8*)(qp + 32);

    f32x4 acc[16];
#pragma unroll
    for (int t = 0; t < 16; t++) acc[t] = f32x4{0.f, 0.f, 0.f, 0.f};

    __builtin_amdgcn_s_setprio(1);
#pragma unroll
    for (int t = 0; t < 16; t++) {
      int col = w * 256 + t * 16 + rl;
      const unsigned short* kp = Kb + (long)col * 64 + hi * 8;
      bf16x8 k0 = *(const bf16x8*)kp;
      bf16x8 k1 = *(const bf16x8*)(kp + 32);
      acc[t] = __builtin_amdgcn_mfma_f32_16x16x32_bf16(qf0, k0, acc[t], 0, 0, 0);
      acc[t] = __builtin_amdgcn_mfma_f32_16x16x32_bf16(qf1, k1, acc[t], 0, 0, 0);
    }
    __builtin_amdgcn_s_setprio(0);

    unsigned mw[4][8];
#pragma unroll
    for (int j = 0; j < 4; j++) {
      int q = q0 + hi * 4 + j;
      const uint4* wp = (const uint4*)(mb + (((long)((b << 10) | q)) << 5) + w * 8);
      uint4 w0 = wp[0], w1 = wp[1];
      mw[j][0] = w0.x; mw[j][1] = w0.y; mw[j][2] = w0.z; mw[j][3] = w0.w;
      mw[j][4] = w1.x; mw[j][5] = w1.y; mw[j][6] = w1.z; mw[j][7] = w1.w;
    }

    float mx[4] = {-3.0e38f, -3.0e38f, -3.0e38f, -3.0e38f};
#pragma unroll
    for (int t = 0; t < 16; t++) {
#pragma unroll
      for (int j = 0; j < 4; j++) {
        float v = ((mw[j][t >> 1] >> (rl + ((t & 1) << 4))) & 1u) ? -1.0e9f : acc[t][j];
        acc[t][j] = v;
        mx[j] = fmaxf(mx[j], v);
      }
    }
#pragma unroll
    for (int j = 0; j < 4; j++) {
      mx[j] = fmaxf(mx[j], __shfl_xor(mx[j], 1));
      mx[j] = fmaxf(mx[j], __shfl_xor(mx[j], 2));
      mx[j] = fmaxf(mx[j], __shfl_xor(mx[j], 4));
      mx[j] = fmaxf(mx[j], __shfl_xor(mx[j], 8));
    }
    if (rl == 0) {
#pragma unroll
      for (int j = 0; j < 4; j++) redm[w][hi * 4 + j] = mx[j];
    }
    __syncthreads();
    float m4[4];
#pragma unroll
    for (int j = 0; j < 4; j++) {
      int r = hi * 4 + j;
      m4[j] = fmaxf(fmaxf(redm[0][r], redm[1][r]), fmaxf(redm[2][r], redm[3][r]));
    }

    float sum[4] = {0.f, 0.f, 0.f, 0.f};
#pragma unroll
    for (int t = 0; t < 16; t++)
#pragma unroll
      for (int j = 0; j < 4; j++) {
        float e = __expf(acc[t][j] - m4[j]);
        acc[t][j] = e;
        sum[j] += e;
      }
#pragma unroll
    for (int j = 0; j < 4; j++) {
      sum[j] += __shfl_xor(sum[j], 1);
      sum[j] += __shfl_xor(sum[j], 2);
      sum[j] += __shfl_xor(sum[j], 4);
      sum[j] += __shfl_xor(sum[j], 8);
    }
    if (rl == 0) {
#pragma unroll
      for (int j = 0; j < 4; j++) reds[w][hi * 4 + j] = sum[j];
    }
    __syncthreads();
    float inv[4];
#pragma unroll
    for (int j = 0; j < 4; j++) {
      int r = hi * 4 + j;
      inv[j] = 1.0f / (reds[0][r] + reds[1][r] + reds[2][r] + reds[3][r]);
    }

#pragma unroll
    for (int t = 0; t < 16; t++) {
      int col = w * 256 + t * 16 + rl;
#pragma unroll
      for (int j = 0; j < 4; j++) {
        int r = hi * 4 + j;
        float p = acc[t][j] * inv[j];
        __builtin_nontemporal_store(p, &attn[abase + (((long)(q0 + r)) << 10) + col]);
        *(unsigned short*)((char*)Pl + r * 2048 + ((col * 2) ^ ((r & 7) << 4))) = f2bf(p);
      }
    }
    __syncthreads();

    f32x4 c2 = f32x4{0.f, 0.f, 0.f, 0.f};
    __builtin_amdgcn_s_setprio(1);
#pragma unroll
    for (int ks = 0; ks < 32; ks++) {
      bf16x8 af = *(const bf16x8*)((const char*)Pl + rl * 2048 + ((ks * 64 + hi * 16) ^ ((rl & 7) << 4)));
      bf16x8 vf = *(const bf16x8*)(Vb + (long)(w * 16 + rl) * 1024 + ks * 32 + hi * 8);
      c2 = __builtin_amdgcn_mfma_f32_16x16x32_bf16(af, vf, c2, 0, 0, 0);
    }
    __builtin_amdgcn_s_setprio(0);
#pragma unroll
    for (int j = 0; j < 4; j++) Pc[(hi * 4 + j) * 64 + w * 16 + rl] = f2bf(c2[j]);
    __syncthreads();
    {
      int qr = tid >> 4, dg = (tid & 15) << 2;
      unsigned long long v = *(const unsigned long long*)&Pc[qr * 64 + dg];
      __builtin_nontemporal_store(
          v, (unsigned long long*)&ctx[((long)(b * 1024 + q0 + qr) << 10) + h * 64 + dg]);
    }
  }
}

extern "C" void kernel_launch(void* const* d_in, const int* in_sizes, int n_in,
                              void* d_out, int out_size, void* d_ws, size_t ws_size,
                              hipStream_t stream) {
  const float* inQ = (const float*)d_in[0];
  const float* inK = (const float*)d_in[1];
  const float* inV = (const float*)d_in[2];
  const unsigned char* mask = (const unsigned char*)d_in[3];
  const float* WQ = (const float*)d_in[4];
  const float* WK = (const float*)d_in[5];
  const float* WV = (const float*)d_in[6];
  const float* WFC = (const float*)d_in[7];
  const float* gamma = (const float*)d_in[8];
  const float* beta = (const float*)d_in[9];

  float* out = (float*)d_out;
  float* attn = out + (size_t)BATCH * SLEN * DMODEL;

  char* ws = (char*)d_ws;
  size_t off = 256;
  int* flag = (int*)ws;
  auto take = [&](size_t bytes) { char* p = ws + off; off += (bytes + 255) & ~255UL; return p; };
  const size_t XB = (size_t)BATCH * SLEN * DMODEL * 2;
  const size_t WB = (size_t)DMODEL * DMODEL * 2;
  unsigned short* Wqb = (unsigned short*)take(WB);
  unsigned short* Wkb = (unsigned short*)take(WB);
  unsigned short* Wvb = (unsigned short*)take(WB);
  unsigned short* Wfcb = (unsigned short*)take(WB);
  unsigned short* Qh = (unsigned short*)take(XB);
  unsigned short* Kh = (unsigned short*)take(XB);
  unsigned short* Vh = (unsigned short*)take(XB);
  unsigned short* Vt = (unsigned short*)take(XB);
  unsigned short* ctx = (unsigned short*)take(XB);
  unsigned* mb = (unsigned*)take((size_t)BATCH * SLEN * 32 * 4);  // 1 MB bitmask

  detect_mask<<<1, 64, 0, stream>>>(mask, flag);
  mask_pack<<<BATCH * SLEN, 256, 0, stream>>>(mask, flag, mb);

  const int n8w = DMODEL * DMODEL / 8;
  cvt_bf16_multi<<<dim3(n8w / 256, 4), 256, 0, stream>>>(WQ, WK, WV, WFC,
                                                         Wqb, Wkb, Wvb, Wfcb, n8w);

  gemm_proj3<<<dim3(8, 64, 3), 256, 0, stream>>>(inQ, inK, inV, Wqb, Wkb, Wvb, Qh, Kh, Vh);

  transpose_v<<<dim3(16, 128), 256, 0, stream>>>(Vh, Vt);

  attn_fused2<<<dim3(1024), 256, 0, stream>>>(Qh, Kh, Vt, mb, attn, ctx);

  gemm_fc_ln<<<dim3(512), 512, 0, stream>>>(ctx, Wfcb, inQ, gamma, beta, out);
}

// Round 8
// 448.327 us; speedup vs baseline: 1.2315x; 1.2315x over previous
//
#include <hip/hip_runtime.h>

typedef __attribute__((ext_vector_type(8))) __bf16 bf16x8;
typedef __attribute__((ext_vector_type(4))) float f32x4;

#define SLEN 1024
#define DMODEL 1024
#define NHEADS 16
#define DKH 64
#define BATCH 8

__device__ __forceinline__ unsigned short f2bf(float f) {
  unsigned u = __builtin_bit_cast(unsigned, f);
  u += 0x7FFFu + ((u >> 16) & 1u);
  return (unsigned short)(u >> 16);
}

__device__ __forceinline__ void gload_lds16(const void* g, void* l) {
  __builtin_amdgcn_global_load_lds((const __attribute__((address_space(1))) unsigned int*)g,
                                   (__attribute__((address_space(3))) unsigned int*)l, 16, 0, 0);
}

// ---------------- mask dtype detection: flag=1 -> byte mask, 0 -> int32 mask
__global__ void detect_mask(const unsigned char* __restrict__ m, int* __restrict__ flag) {
  int t = threadIdx.x;
  unsigned any = 0;
  for (int j = t; j < 4096; j += 64) any |= m[j * 4 + 1];
  unsigned long long b = __ballot(any != 0);
  if (t == 0) *flag = (b != 0) ? 1 : 0;
}

// ---------------- bit-pack mask: one block per (b,q) row of 1024 -> 32 words
__global__ __launch_bounds__(256) void mask_pack(const unsigned char* __restrict__ m,
                                                 const int* __restrict__ flagp,
                                                 unsigned* __restrict__ mb) {
  long base = (long)blockIdx.x << 10;
  int tid = threadIdx.x;
  int flag = *flagp;
  unsigned nib;
  if (flag) {
    uchar4 v = ((const uchar4*)(m + base))[tid];
    nib = (v.x ? 1u : 0u) | (v.y ? 2u : 0u) | (v.z ? 4u : 0u) | (v.w ? 8u : 0u);
  } else {
    int4 v = ((const int4*)((const int*)m + base))[tid];
    nib = (v.x ? 1u : 0u) | (v.y ? 2u : 0u) | (v.z ? 4u : 0u) | (v.w ? 8u : 0u);
  }
  __shared__ unsigned char nibs[256];
  nibs[tid] = (unsigned char)nib;
  __syncthreads();
  if (tid < 32) {
    unsigned wv = 0;
#pragma unroll
    for (int i = 0; i < 8; i++) wv |= ((unsigned)nibs[tid * 8 + i]) << (i * 4);
    mb[((long)blockIdx.x << 5) + tid] = wv;
  }
}

// ---------------- fp32 -> bf16 bulk convert, up to 4 tensors via blockIdx.y
__global__ __launch_bounds__(256) void cvt_bf16_multi(
    const float* __restrict__ p0, const float* __restrict__ p1,
    const float* __restrict__ p2, const float* __restrict__ p3,
    unsigned short* __restrict__ o0, unsigned short* __restrict__ o1,
    unsigned short* __restrict__ o2, unsigned short* __restrict__ o3, int n8) {
  int which = blockIdx.y;
  const float* in = which == 0 ? p0 : which == 1 ? p1 : which == 2 ? p2 : p3;
  unsigned short* o = which == 0 ? o0 : which == 1 ? o1 : which == 2 ? o2 : o3;
  int i = blockIdx.x * 256 + threadIdx.x;
  if (i >= n8) return;
  const float4* p = (const float4*)in;
  float4 f0 = p[2 * i], f1 = p[2 * i + 1];
  union { unsigned short us[8]; uint4 v; } pk;
  pk.us[0] = f2bf(f0.x); pk.us[1] = f2bf(f0.y); pk.us[2] = f2bf(f0.z); pk.us[3] = f2bf(f0.w);
  pk.us[4] = f2bf(f1.x); pk.us[5] = f2bf(f1.y); pk.us[6] = f2bf(f1.z); pk.us[7] = f2bf(f1.w);
  ((uint4*)o)[i] = pk.v;
}

// ---------------- transpose V per (b,h): [1024][64] -> [64][1024]
__global__ __launch_bounds__(256) void transpose_v(const unsigned short* __restrict__ Vh,
                                                   unsigned short* __restrict__ Vt) {
  __shared__ unsigned short t[64][65];
  int s0 = blockIdx.x * 64;
  long zo = (long)blockIdx.y * (SLEN * DKH);
  int tid = threadIdx.x;
  for (int i = tid; i < 4096; i += 256) {
    int r = i >> 6, c = i & 63;
    t[r][c] = Vh[zo + (long)(s0 + r) * 64 + c];
  }
  __syncthreads();
  for (int i = tid; i < 4096; i += 256) {
    int d = i >> 6, sc = i & 63;
    Vt[zo + (long)d * SLEN + s0 + sc] = t[sc][d];
  }
}

// ---------------- merged QKV projection GEMM (z = 0/1/2 -> Q/K/V)
// bf16 NT, BK=64, XOR-swizzled LDS both operands; grid (64 m, 8 n, 3)
__global__ __launch_bounds__(256) void gemm_proj3(
    const unsigned short* __restrict__ A0, const unsigned short* __restrict__ A1,
    const unsigned short* __restrict__ A2, const unsigned short* __restrict__ B0,
    const unsigned short* __restrict__ B1, const unsigned short* __restrict__ B2,
    unsigned short* __restrict__ O0, unsigned short* __restrict__ O1,
    unsigned short* __restrict__ O2) {
  const int z = blockIdx.z;
  const unsigned short* Ab = z == 0 ? A0 : z == 1 ? A1 : A2;
  const unsigned short* Bb = z == 0 ? B0 : z == 1 ? B1 : B2;
  unsigned short* obf = z == 0 ? O0 : z == 1 ? O1 : O2;
  const float scale = z == 0 ? 0.125f : 1.0f;

  const int m0 = blockIdx.x * 128;
  const int n0 = blockIdx.y * 128;
  const int tid = threadIdx.x;
  const int l = tid & 63;
  const int w = tid >> 6;
  const int wr = w >> 1, wc = w & 1;
  const int rl = l & 15, hi = l >> 4;

  __shared__ __attribute__((aligned(16))) unsigned short As[128 * 64];  // 16 KB swz
  __shared__ __attribute__((aligned(16))) unsigned short Bs[128 * 64];  // 16 KB swz

  f32x4 acc[4][4];
#pragma unroll
  for (int i = 0; i < 4; i++)
#pragma unroll
    for (int j = 0; j < 4; j++) acc[i][j] = f32x4{0.f, 0.f, 0.f, 0.f};

  for (int k0 = 0; k0 < 1024; k0 += 64) {
    __syncthreads();
#pragma unroll
    for (int i = 0; i < 4; i++) {
      int o = (i * 256 + tid) * 16;
      int row = o >> 7, cb = o & 127;
      int cbs = cb ^ ((row & 7) << 4);
      gload_lds16(Ab + (long)(m0 + row) * 1024 + k0 + (cbs >> 1), (char*)As + o);
    }
#pragma unroll
    for (int i = 0; i < 4; i++) {
      int o = (i * 256 + tid) * 16;
      int row = o >> 7, cb = o & 127;
      int cbs = cb ^ ((row & 7) << 4);
      gload_lds16(Bb + (long)(n0 + row) * 1024 + k0 + (cbs >> 1), (char*)Bs + o);
    }
    __syncthreads();

#pragma unroll
    for (int ks = 0; ks < 2; ks++) {
      int kb = ks * 64 + hi * 16;
      bf16x8 af[4], bfr[4];
#pragma unroll
      for (int mi = 0; mi < 4; mi++) {
        int row = wr * 64 + mi * 16 + rl;
        af[mi] = *(const bf16x8*)((const char*)As + row * 128 + (kb ^ ((row & 7) << 4)));
      }
#pragma unroll
      for (int ni = 0; ni < 4; ni++) {
        int row = wc * 64 + ni * 16 + rl;
        bfr[ni] = *(const bf16x8*)((const char*)Bs + row * 128 + (kb ^ ((row & 7) << 4)));
      }
#pragma unroll
      for (int mi = 0; mi < 4; mi++)
#pragma unroll
        for (int ni = 0; ni < 4; ni++)
          acc[mi][ni] = __builtin_amdgcn_mfma_f32_16x16x32_bf16(af[mi], bfr[ni], acc[mi][ni], 0, 0, 0);
    }
  }

  const int r0 = hi << 2;
#pragma unroll
  for (int mi = 0; mi < 4; mi++) {
#pragma unroll
    for (int ni = 0; ni < 4; ni++) {
      f32x4 v = acc[mi][ni];
      int row = m0 + wr * 64 + mi * 16 + r0;
      int col = n0 + wc * 64 + ni * 16 + rl;
#pragma unroll
      for (int j = 0; j < 4; j++) {
        int rr = row + j;
        long idx = (((long)((rr >> 10) * 16 + (col >> 6)) * 1024 + (rr & 1023)) << 6) + (col & 63);
        obf[idx] = f2bf(v[j] * scale);
      }
    }
  }
}

// ---------------- FC GEMM: fp32 out row-major, BK=64 + swizzle
__global__ __launch_bounds__(256) void gemm_fc(
    const unsigned short* __restrict__ Ab, const unsigned short* __restrict__ Bb,
    float* __restrict__ of32) {
  const int m0 = blockIdx.x * 128;
  const int n0 = blockIdx.y * 128;
  const int tid = threadIdx.x;
  const int l = tid & 63;
  const int w = tid >> 6;
  const int wr = w >> 1, wc = w & 1;
  const int rl = l & 15, hi = l >> 4;

  __shared__ __attribute__((aligned(16))) unsigned short As[128 * 64];
  __shared__ __attribute__((aligned(16))) unsigned short Bs[128 * 64];

  f32x4 acc[4][4];
#pragma unroll
  for (int i = 0; i < 4; i++)
#pragma unroll
    for (int j = 0; j < 4; j++) acc[i][j] = f32x4{0.f, 0.f, 0.f, 0.f};

  for (int k0 = 0; k0 < 1024; k0 += 64) {
    __syncthreads();
#pragma unroll
    for (int i = 0; i < 4; i++) {
      int o = (i * 256 + tid) * 16;
      int row = o >> 7, cb = o & 127;
      int cbs = cb ^ ((row & 7) << 4);
      gload_lds16(Ab + (long)(m0 + row) * 1024 + k0 + (cbs >> 1), (char*)As + o);
    }
#pragma unroll
    for (int i = 0; i < 4; i++) {
      int o = (i * 256 + tid) * 16;
      int row = o >> 7, cb = o & 127;
      int cbs = cb ^ ((row & 7) << 4);
      gload_lds16(Bb + (long)(n0 + row) * 1024 + k0 + (cbs >> 1), (char*)Bs + o);
    }
    __syncthreads();

#pragma unroll
    for (int ks = 0; ks < 2; ks++) {
      int kb = ks * 64 + hi * 16;
      bf16x8 af[4], bfr[4];
#pragma unroll
      for (int mi = 0; mi < 4; mi++) {
        int row = wr * 64 + mi * 16 + rl;
        af[mi] = *(const bf16x8*)((const char*)As + row * 128 + (kb ^ ((row & 7) << 4)));
      }
#pragma unroll
      for (int ni = 0; ni < 4; ni++) {
        int row = wc * 64 + ni * 16 + rl;
        bfr[ni] = *(const bf16x8*)((const char*)Bs + row * 128 + (kb ^ ((row & 7) << 4)));
      }
#pragma unroll
      for (int mi = 0; mi < 4; mi++)
#pragma unroll
        for (int ni = 0; ni < 4; ni++)
          acc[mi][ni] = __builtin_amdgcn_mfma_f32_16x16x32_bf16(af[mi], bfr[ni], acc[mi][ni], 0, 0, 0);
    }
  }

  const int r0 = hi << 2;
#pragma unroll
  for (int mi = 0; mi < 4; mi++) {
#pragma unroll
    for (int ni = 0; ni < 4; ni++) {
      f32x4 v = acc[mi][ni];
      int row = m0 + wr * 64 + mi * 16 + r0;
      int col = n0 + wc * 64 + ni * 16 + rl;
#pragma unroll
      for (int j = 0; j < 4; j++)
        of32[((long)(row + j) << 10) + col] = v[j];
    }
  }
}

// ---------------- fused scores+mask+softmax+attnwrite+PV, K/V L2-direct
// 1-D grid 1024; XCD-locality decode: each XCD owns 16 z's (K+V = 4 MB = its L2)
__global__ __launch_bounds__(256) void attn_fused2(
    const unsigned short* __restrict__ Qh, const unsigned short* __restrict__ Kh,
    const unsigned short* __restrict__ Vt, const unsigned* __restrict__ mb,
    float* __restrict__ attn, unsigned short* __restrict__ ctx) {
  const int lin = blockIdx.x;
  const int xcd = lin & 7;
  const int k_ = lin >> 3;
  const int z = xcd + ((k_ >> 3) << 3);  // z % 8 == xcd
  const int qt = k_ & 7;
  const int b = z >> 4, h = z & 15;
  const int tid = threadIdx.x, l = tid & 63, w = tid >> 6;
  const int rl = l & 15, hi = l >> 4;

  __shared__ __attribute__((aligned(16))) unsigned short Pl[16 * 1024];  // 32 KB swz
  __shared__ __attribute__((aligned(16))) unsigned short Pc[16 * 64];    // 2 KB
  __shared__ float redm[4][16], reds[4][16];

  const long bh = (long)z * (SLEN * DKH);
  const unsigned short* Kb = Kh + bh;
  const unsigned short* Vb = Vt + bh;
  const long abase = (long)z << 20;

  for (int s = 0; s < 8; s++) {
    const int q0 = qt * 128 + s * 16;
    const unsigned short* qp = Qh + bh + (long)(q0 + rl) * 64 + hi * 8;
    bf16x8 qf0 = *(const bf16x8*)qp;
    bf16x8 qf1 = *(const bf16x8*)(qp + 32);

    f32x4 acc[16];
#pragma unroll
    for (int t = 0; t < 16; t++) acc[t] = f32x4{0.f, 0.f, 0.f, 0.f};

    __builtin_amdgcn_s_setprio(1);
#pragma unroll
    for (int t = 0; t < 16; t++) {
      int col = w * 256 + t * 16 + rl;
      const unsigned short* kp = Kb + (long)col * 64 + hi * 8;
      bf16x8 k0 = *(const bf16x8*)kp;
      bf16x8 k1 = *(const bf16x8*)(kp + 32);
      acc[t] = __builtin_amdgcn_mfma_f32_16x16x32_bf16(qf0, k0, acc[t], 0, 0, 0);
      acc[t] = __builtin_amdgcn_mfma_f32_16x16x32_bf16(qf1, k1, acc[t], 0, 0, 0);
    }
    __builtin_amdgcn_s_setprio(0);

    unsigned mw[4][8];
#pragma unroll
    for (int j = 0; j < 4; j++) {
      int q = q0 + hi * 4 + j;
      const uint4* wp = (const uint4*)(mb + (((long)((b << 10) | q)) << 5) + w * 8);
      uint4 w0 = wp[0], w1 = wp[1];
      mw[j][0] = w0.x; mw[j][1] = w0.y; mw[j][2] = w0.z; mw[j][3] = w0.w;
      mw[j][4] = w1.x; mw[j][5] = w1.y; mw[j][6] = w1.z; mw[j][7] = w1.w;
    }

    float mx[4] = {-3.0e38f, -3.0e38f, -3.0e38f, -3.0e38f};
#pragma unroll
    for (int t = 0; t < 16; t++) {
#pragma unroll
      for (int j = 0; j < 4; j++) {
        float v = ((mw[j][t >> 1] >> (rl + ((t & 1) << 4))) & 1u) ? -1.0e9f : acc[t][j];
        acc[t][j] = v;
        mx[j] = fmaxf(mx[j], v);
      }
    }
#pragma unroll
    for (int j = 0; j < 4; j++) {
      mx[j] = fmaxf(mx[j], __shfl_xor(mx[j], 1));
      mx[j] = fmaxf(mx[j], __shfl_xor(mx[j], 2));
      mx[j] = fmaxf(mx[j], __shfl_xor(mx[j], 4));
      mx[j] = fmaxf(mx[j], __shfl_xor(mx[j], 8));
    }
    if (rl == 0) {
#pragma unroll
      for (int j = 0; j < 4; j++) redm[w][hi * 4 + j] = mx[j];
    }
    __syncthreads();
    float m4[4];
#pragma unroll
    for (int j = 0; j < 4; j++) {
      int r = hi * 4 + j;
      m4[j] = fmaxf(fmaxf(redm[0][r], redm[1][r]), fmaxf(redm[2][r], redm[3][r]));
    }

    float sum[4] = {0.f, 0.f, 0.f, 0.f};
#pragma unroll
    for (int t = 0; t < 16; t++)
#pragma unroll
      for (int j = 0; j < 4; j++) {
        float e = __expf(acc[t][j] - m4[j]);
        acc[t][j] = e;
        sum[j] += e;
      }
#pragma unroll
    for (int j = 0; j < 4; j++) {
      sum[j] += __shfl_xor(sum[j], 1);
      sum[j] += __shfl_xor(sum[j], 2);
      sum[j] += __shfl_xor(sum[j], 4);
      sum[j] += __shfl_xor(sum[j], 8);
    }
    if (rl == 0) {
#pragma unroll
      for (int j = 0; j < 4; j++) reds[w][hi * 4 + j] = sum[j];
    }
    __syncthreads();
    float inv[4];
#pragma unroll
    for (int j = 0; j < 4; j++) {
      int r = hi * 4 + j;
      inv[j] = 1.0f / (reds[0][r] + reds[1][r] + reds[2][r] + reds[3][r]);
    }

#pragma unroll
    for (int t = 0; t < 16; t++) {
      int col = w * 256 + t * 16 + rl;
#pragma unroll
      for (int j = 0; j < 4; j++) {
        int r = hi * 4 + j;
        float p = acc[t][j] * inv[j];
        __builtin_nontemporal_store(p, &attn[abase + (((long)(q0 + r)) << 10) + col]);
        *(unsigned short*)((char*)Pl + r * 2048 + ((col * 2) ^ ((r & 7) << 4))) = f2bf(p);
      }
    }
    __syncthreads();

    f32x4 c2 = f32x4{0.f, 0.f, 0.f, 0.f};
    __builtin_amdgcn_s_setprio(1);
#pragma unroll
    for (int ks = 0; ks < 32; ks++) {
      bf16x8 af = *(const bf16x8*)((const char*)Pl + rl * 2048 + ((ks * 64 + hi * 16) ^ ((rl & 7) << 4)));
      bf16x8 vf = *(const bf16x8*)(Vb + (long)(w * 16 + rl) * 1024 + ks * 32 + hi * 8);
      c2 = __builtin_amdgcn_mfma_f32_16x16x32_bf16(af, vf, c2, 0, 0, 0);
    }
    __builtin_amdgcn_s_setprio(0);
#pragma unroll
    for (int j = 0; j < 4; j++) Pc[(hi * 4 + j) * 64 + w * 16 + rl] = f2bf(c2[j]);
    __syncthreads();
    {
      int qr = tid >> 4, dg = (tid & 15) << 2;
      unsigned long long v = *(const unsigned long long*)&Pc[qr * 64 + dg];
      __builtin_nontemporal_store(
          v, (unsigned long long*)&ctx[((long)(b * 1024 + q0 + qr) << 10) + h * 64 + dg]);
    }
  }
}

// ---------------- residual + LayerNorm, one block per row
__global__ __launch_bounds__(256) void ln_kernel(const float* __restrict__ fc,
                                                 const float* __restrict__ inQ,
                                                 const float* __restrict__ gamma,
                                                 const float* __restrict__ beta,
                                                 float* __restrict__ out) {
  long base = (long)blockIdx.x << 10;
  int tid = threadIdx.x, l = tid & 63, w = tid >> 6;
  float4 a = ((const float4*)(fc + base))[tid];
  float4 b = ((const float4*)(inQ + base))[tid];
  float4 x; x.x = a.x + b.x; x.y = a.y + b.y; x.z = a.z + b.z; x.w = a.w + b.w;
  float s = x.x + x.y + x.z + x.w;
  float q = x.x * x.x + x.y * x.y + x.z * x.z + x.w * x.w;
  for (int o = 32; o; o >>= 1) { s += __shfl_xor(s, o); q += __shfl_xor(q, o); }
  __shared__ float rs[4], rq[4];
  if (l == 0) { rs[w] = s; rq[w] = q; }
  __syncthreads();
  s = rs[0] + rs[1] + rs[2] + rs[3];
  q = rq[0] + rq[1] + rq[2] + rq[3];
  float mu = s * (1.0f / 1024.0f);
  float var = q * (1.0f / 1024.0f) - mu * mu;
  float rstd = rsqrtf(var + 1e-5f);
  float4 g = ((const float4*)gamma)[tid];
  float4 be = ((const float4*)beta)[tid];
  float4 o4;
  o4.x = (x.x - mu) * rstd * g.x + be.x;
  o4.y = (x.y - mu) * rstd * g.y + be.y;
  o4.z = (x.z - mu) * rstd * g.z + be.z;
  o4.w = (x.w - mu) * rstd * g.w + be.w;
  ((float4*)(out + base))[tid] = o4;
}

extern "C" void kernel_launch(void* const* d_in, const int* in_sizes, int n_in,
                              void* d_out, int out_size, void* d_ws, size_t ws_size,
                              hipStream_t stream) {
  const float* inQ = (const float*)d_in[0];
  const float* inK = (const float*)d_in[1];
  const float* inV = (const float*)d_in[2];
  const unsigned char* mask = (const unsigned char*)d_in[3];
  const float* WQ = (const float*)d_in[4];
  const float* WK = (const float*)d_in[5];
  const float* WV = (const float*)d_in[6];
  const float* WFC = (const float*)d_in[7];
  const float* gamma = (const float*)d_in[8];
  const float* beta = (const float*)d_in[9];

  float* out = (float*)d_out;
  float* attn = out + (size_t)BATCH * SLEN * DMODEL;

  char* ws = (char*)d_ws;
  size_t off = 256;
  int* flag = (int*)ws;
  auto take = [&](size_t bytes) { char* p = ws + off; off += (bytes + 255) & ~255UL; return p; };
  const size_t XB = (size_t)BATCH * SLEN * DMODEL * 2;
  const size_t WB = (size_t)DMODEL * DMODEL * 2;
  unsigned short* Xq = (unsigned short*)take(XB);
  unsigned short* Xk = (unsigned short*)take(XB);
  unsigned short* Xv = (unsigned short*)take(XB);
  unsigned short* Wqb = (unsigned short*)take(WB);
  unsigned short* Wkb = (unsigned short*)take(WB);
  unsigned short* Wvb = (unsigned short*)take(WB);
  unsigned short* Wfcb = (unsigned short*)take(WB);
  unsigned short* Qh = (unsigned short*)take(XB);
  unsigned short* Kh = (unsigned short*)take(XB);
  unsigned short* Vh = (unsigned short*)take(XB);
  unsigned short* Vt = (unsigned short*)take(XB);
  unsigned short* ctx = (unsigned short*)take(XB);
  float* fc = (float*)take((size_t)BATCH * SLEN * DMODEL * 4);
  unsigned* mb = (unsigned*)take((size_t)BATCH * SLEN * 32 * 4);  // 1 MB bitmask

  detect_mask<<<1, 64, 0, stream>>>(mask, flag);
  mask_pack<<<BATCH * SLEN, 256, 0, stream>>>(mask, flag, mb);

  const int n8x = BATCH * SLEN * DMODEL / 8;
  const int n8w = DMODEL * DMODEL / 8;
  cvt_bf16_multi<<<dim3(n8x / 256, 3), 256, 0, stream>>>(inQ, inK, inV, nullptr,
                                                         Xq, Xk, Xv, nullptr, n8x);
  cvt_bf16_multi<<<dim3(n8w / 256, 4), 256, 0, stream>>>(WQ, WK, WV, WFC,
                                                         Wqb, Wkb, Wvb, Wfcb, n8w);

  gemm_proj3<<<dim3(64, 8, 3), 256, 0, stream>>>(Xq, Xk, Xv, Wqb, Wkb, Wvb, Qh, Kh, Vh);

  transpose_v<<<dim3(16, 128), 256, 0, stream>>>(Vh, Vt);

  attn_fused2<<<dim3(1024), 256, 0, stream>>>(Qh, Kh, Vt, mb, attn, ctx);

  gemm_fc<<<dim3(64, 8), 256, 0, stream>>>(ctx, Wfcb, fc);

  ln_kernel<<<BATCH * SLEN, 256, 0, stream>>>(fc, inQ, gamma, beta, out);
}